// Round 1
// 11010.431 us; speedup vs baseline: 1.3798x; 1.3798x over previous
//
#include <hip/hip_runtime.h>

// Decoder ODE-RNN (GRU + Euler-2 ODE + softmax emit). Inputs/outputs FLOAT32.
// f32 GEMM emulated via bf16x3 splitting (6 MFMAs: hh+hm+mh+mm+hl+lh).
// R1 change vs 15.2ms baseline:
//   - weights transposed AND pre-split to bf16 hi/mid/lo ONCE at setup
//   - GEMM producers write h/hr/tbf pre-split (epilogue split3) -> consumers
//     stage pure bf16, no per-iter split VALU on the critical path
//   - BK 32->64 (serial k-iters per step 200->100, barriers halved)
//   - register prefetch of next k-tile overlaps global latency with MFMA
// Numerics bit-identical to baseline (same split values, same MFMA order).

typedef __bf16 bf16_t;
typedef __bf16 bf16x8 __attribute__((ext_vector_type(8)));
typedef float  f32x4  __attribute__((ext_vector_type(4)));

#define BM 64
#define BN 64
#define BK 64
#define LDT 72   // padded LDS row stride (elems): 144B rows -> ~2-way bank aliasing (free)

__device__ __forceinline__ float sigmoidf_(float x) { return 1.f / (1.f + expf(-x)); }

__device__ __forceinline__ void split3(float v, bf16_t& h, bf16_t& m, bf16_t& l) {
  h = (bf16_t)v; float r1 = v - (float)h;
  m = (bf16_t)r1; float r2 = r1 - (float)m;
  l = (bf16_t)r2;
}

// flag-aware 8-float load from HARNESS inputs (f32 vs bf16 decided at runtime)
__device__ __forceinline__ void loadf8(const void* p, size_t idx, int isf32, float out[8]) {
  if (isf32) {
    const float* q = (const float*)p + idx;
    f32x4 a = *(const f32x4*)q;
    f32x4 b = *(const f32x4*)(q + 4);
    out[0]=a[0]; out[1]=a[1]; out[2]=a[2]; out[3]=a[3];
    out[4]=b[0]; out[5]=b[1]; out[6]=b[2]; out[7]=b[3];
  } else {
    bf16x8 v = *(const bf16x8*)((const bf16_t*)p + idx);
#pragma unroll
    for (int i = 0; i < 8; i++) out[i] = (float)v[i];
  }
}
__device__ __forceinline__ float loadf(const void* p, int idx, int isf32) {
  return isf32 ? ((const float*)p)[idx] : (float)((const bf16_t*)p)[idx];
}

__global__ void k_probe(const unsigned int* ts_raw, int* flag) {
  *flag = (ts_raw[0] == 0u) ? 1 : 0;   // 1 = f32 inputs, 0 = bf16 inputs
}

// ---------------- split-precision GEMM core: C[64x64] tile.
// A: pre-split bf16x3 row-major [M][lda]. B: pre-split bf16x3 [N][K].
// CATX: A is concat(h[512,1024] presplit, data[:,t,:] harness dtype) along K (K=1536);
//       the x-part is loaded raw + split in-register (hidden under MFMA).
template<bool CATX>
__device__ __forceinline__ void gemm6(
    const bf16_t* __restrict__ Ah, const bf16_t* __restrict__ Am, const bf16_t* __restrict__ Al,
    int lda,
    const void* __restrict__ X, int isf32, int t,
    const bf16_t* __restrict__ Bh, const bf16_t* __restrict__ Bm, const bf16_t* __restrict__ Bl,
    int K,
    f32x4 acc[2][2])
{
  __shared__ __align__(16) bf16_t As[3][BM * LDT];
  __shared__ __align__(16) bf16_t Bs[3][BN * LDT];

  const int tid  = threadIdx.x;
  const int srow = tid >> 2;            // 0..63 staging row
  const int sc   = (tid & 3) << 4;      // 0,16,32,48 (16-elem col chunk)
  const int mBase = blockIdx.y * BM;
  const int nBase = blockIdx.x * BN;
  const int arow = mBase + srow;
  const int brow = nBase + srow;

  const int lane = tid & 63;
  const int wid  = tid >> 6;
  const int wm   = (wid & 1) * 32;
  const int wn   = (wid >> 1) * 32;
  const int q8   = (lane >> 4) << 3;    // 0,8,16,24
  const int l16  = lane & 15;

  f32x4 z = {0.f, 0.f, 0.f, 0.f};
#pragma unroll
  for (int i = 0; i < 2; i++)
#pragma unroll
    for (int j = 0; j < 2; j++) acc[i][j] = z;

  bf16x8 pA[3][2], pB[3][2];   // prefetch regs: 3 splits x 2 bf16x8 (16 elems)

  auto loadA = [&](int k0) {
    int gk = k0 + sc;                           // chunk never straddles 1024 (BK|1024)
    if (CATX && gk >= 1024) {
      size_t off = (size_t)arow * 32768 + (size_t)t * 512 + (size_t)(gk - 1024);
      float v[16];
      loadf8(X, off,     isf32, v);
      loadf8(X, off + 8, isf32, v + 8);
#pragma unroll
      for (int u8 = 0; u8 < 2; u8++)
#pragma unroll
        for (int j = 0; j < 8; j++) {
          bf16_t h, m, l; split3(v[u8 * 8 + j], h, m, l);
          pA[0][u8][j] = h; pA[1][u8][j] = m; pA[2][u8][j] = l;
        }
    } else {
      size_t off = (size_t)arow * lda + gk;
      pA[0][0] = *(const bf16x8*)(Ah + off); pA[0][1] = *(const bf16x8*)(Ah + off + 8);
      pA[1][0] = *(const bf16x8*)(Am + off); pA[1][1] = *(const bf16x8*)(Am + off + 8);
      pA[2][0] = *(const bf16x8*)(Al + off); pA[2][1] = *(const bf16x8*)(Al + off + 8);
    }
  };
  auto loadB = [&](int k0) {
    size_t off = (size_t)brow * K + k0 + sc;
    pB[0][0] = *(const bf16x8*)(Bh + off); pB[0][1] = *(const bf16x8*)(Bh + off + 8);
    pB[1][0] = *(const bf16x8*)(Bm + off); pB[1][1] = *(const bf16x8*)(Bm + off + 8);
    pB[2][0] = *(const bf16x8*)(Bl + off); pB[2][1] = *(const bf16x8*)(Bl + off + 8);
  };

  loadA(0); loadB(0);

  for (int k0 = 0; k0 < K; k0 += BK) {
    const int wrow = srow * LDT + sc;
#pragma unroll
    for (int p = 0; p < 3; p++) {
      *(bf16x8*)&As[p][wrow]     = pA[p][0];
      *(bf16x8*)&As[p][wrow + 8] = pA[p][1];
      *(bf16x8*)&Bs[p][wrow]     = pB[p][0];
      *(bf16x8*)&Bs[p][wrow + 8] = pB[p][1];
    }
    __syncthreads();

    // prefetch next k-tile: issues global loads that overlap ds_read+MFMA below
    if (k0 + BK < K) { loadA(k0 + BK); loadB(k0 + BK); }

#pragma unroll
    for (int kk = 0; kk < BK; kk += 32) {
      bf16x8 a[2][3], b[2][3];
#pragma unroll
      for (int p = 0; p < 3; p++) {
        a[0][p] = *(const bf16x8*)&As[p][(wm +      l16) * LDT + kk + q8];
        a[1][p] = *(const bf16x8*)&As[p][(wm + 16 + l16) * LDT + kk + q8];
        b[0][p] = *(const bf16x8*)&Bs[p][(wn +      l16) * LDT + kk + q8];
        b[1][p] = *(const bf16x8*)&Bs[p][(wn + 16 + l16) * LDT + kk + q8];
      }
#pragma unroll
      for (int mi = 0; mi < 2; mi++)
#pragma unroll
        for (int ni = 0; ni < 2; ni++) {
          f32x4 c = acc[mi][ni];
          c = __builtin_amdgcn_mfma_f32_16x16x32_bf16(a[mi][0], b[ni][0], c, 0, 0, 0); // hh
          c = __builtin_amdgcn_mfma_f32_16x16x32_bf16(a[mi][0], b[ni][1], c, 0, 0, 0); // hm
          c = __builtin_amdgcn_mfma_f32_16x16x32_bf16(a[mi][1], b[ni][0], c, 0, 0, 0); // mh
          c = __builtin_amdgcn_mfma_f32_16x16x32_bf16(a[mi][1], b[ni][1], c, 0, 0, 0); // mm
          c = __builtin_amdgcn_mfma_f32_16x16x32_bf16(a[mi][0], b[ni][2], c, 0, 0, 0); // hl
          c = __builtin_amdgcn_mfma_f32_16x16x32_bf16(a[mi][2], b[ni][0], c, 0, 0, 0); // lh
          acc[mi][ni] = c;
        }
    }
    __syncthreads();
  }
}

#define EPI_COORDS \
  const int lane = threadIdx.x & 63; \
  const int wid  = threadIdx.x >> 6; \
  const int row0 = blockIdx.y * BM + (wid & 1) * 32 + ((lane >> 4) << 2); \
  const int col0 = blockIdx.x * BN + (wid >> 1) * 32 + (lane & 15);

// ---------------- gates: u = sigmoid([h,x]@Wu + bu) ; r likewise ; hr = h*r (bf16x3 out)
__global__ __launch_bounds__(256, 1) void k_gates(
    const bf16_t* __restrict__ hAh, const bf16_t* __restrict__ hAm, const bf16_t* __restrict__ hAl,
    const float* __restrict__ hAf,
    const void* __restrict__ data, int t,
    const bf16_t* __restrict__ Wh, const bf16_t* __restrict__ Wm, const bf16_t* __restrict__ Wl,
    const void* __restrict__ bu, const void* __restrict__ br,
    float* __restrict__ u_f32,
    bf16_t* __restrict__ hrh, bf16_t* __restrict__ hrm, bf16_t* __restrict__ hrl,
    const int* __restrict__ flg)
{
  const int isf32 = *flg;
  f32x4 acc[2][2];
  gemm6<true>(hAh, hAm, hAl, 1024, data, isf32, t, Wh, Wm, Wl, 1536, acc);
  EPI_COORDS
#pragma unroll
  for (int mi = 0; mi < 2; mi++)
#pragma unroll
    for (int ni = 0; ni < 2; ni++)
#pragma unroll
      for (int r = 0; r < 4; r++) {
        int m = row0 + mi * 16 + r;
        int n = col0 + ni * 16;
        float v = acc[mi][ni][r];
        if (n < 1024) {
          u_f32[m * 1024 + n] = sigmoidf_(v + loadf(bu, n, isf32));
        } else {
          int nn = n - 1024;
          float rr = sigmoidf_(v + loadf(br, nn, isf32));
          float hv = hAf[m * 1024 + nn] * rr;
          bf16_t h, mm_, l; split3(hv, h, mm_, l);
          int idx = m * 1024 + nn;
          hrh[idx] = h; hrm[idx] = mm_; hrl[idx] = l;
        }
      }
}

// ---------------- candidate + GRU blend: n = [hr,x]@Wn + bn ; h1 = (1-u)*n + u*h
__global__ __launch_bounds__(256, 1) void k_cand(
    const bf16_t* __restrict__ hrh, const bf16_t* __restrict__ hrm, const bf16_t* __restrict__ hrl,
    const void* __restrict__ data, int t,
    const bf16_t* __restrict__ Wh, const bf16_t* __restrict__ Wm, const bf16_t* __restrict__ Wl,
    const void* __restrict__ bn,
    const float* __restrict__ u_f32, const float* __restrict__ h_f32,
    float* __restrict__ h1f,
    bf16_t* __restrict__ h1h, bf16_t* __restrict__ h1m, bf16_t* __restrict__ h1l,
    const int* __restrict__ flg)
{
  const int isf32 = *flg;
  f32x4 acc[2][2];
  gemm6<true>(hrh, hrm, hrl, 1024, data, isf32, t, Wh, Wm, Wl, 1536, acc);
  EPI_COORDS
#pragma unroll
  for (int mi = 0; mi < 2; mi++)
#pragma unroll
    for (int ni = 0; ni < 2; ni++)
#pragma unroll
      for (int r = 0; r < 4; r++) {
        int m = row0 + mi * 16 + r;
        int n = col0 + ni * 16;
        int idx = m * 1024 + n;
        float nv = acc[mi][ni][r] + loadf(bn, n, isf32);
        float u = u_f32[idx];
        float h1 = (1.f - u) * nv + u * h_f32[idx];
        h1 = fminf(fmaxf(h1, -1e6f), 1e6f);   // insurance clamp
        h1f[idx] = h1;
        bf16_t h, mm_, l; split3(h1, h, mm_, l);
        h1h[idx] = h; h1m[idx] = mm_; h1l[idx] = l;
      }
}

// ---------------- euler stage A: tbf = tanh(h@W1 + b1), N padded to 128 (cols>=100 are 0)
__global__ __launch_bounds__(256, 1) void k_tanh(
    const bf16_t* __restrict__ hh, const bf16_t* __restrict__ hm, const bf16_t* __restrict__ hl,
    const bf16_t* __restrict__ Wh, const bf16_t* __restrict__ Wm, const bf16_t* __restrict__ Wl,
    const void* __restrict__ b1,
    bf16_t* __restrict__ th, bf16_t* __restrict__ tm, bf16_t* __restrict__ tl,
    const int* __restrict__ flg)
{
  const int isf32 = *flg;
  f32x4 acc[2][2];
  gemm6<false>(hh, hm, hl, 1024, nullptr, 0, 0, Wh, Wm, Wl, 1024, acc);
  EPI_COORDS
#pragma unroll
  for (int mi = 0; mi < 2; mi++)
#pragma unroll
    for (int ni = 0; ni < 2; ni++)
#pragma unroll
      for (int r = 0; r < 4; r++) {
        int m = row0 + mi * 16 + r;
        int n = col0 + ni * 16;
        float b = (n < 100) ? loadf(b1, n, isf32) : 0.f;
        float tv = tanhf(acc[mi][ni][r] + b);
        bf16_t h, mm_, l; split3(tv, h, mm_, l);
        int idx = m * 128 + n;
        th[idx] = h; tm[idx] = mm_; tl[idx] = l;
      }
}

// ---------------- euler stage B: h_out = h_prev + (dt/2)*(tbf@W2 + b2)
template<bool WRITE_STATES>
__global__ __launch_bounds__(256, 1) void k_euler(
    const bf16_t* __restrict__ th, const bf16_t* __restrict__ tm, const bf16_t* __restrict__ tl,
    const bf16_t* __restrict__ Wh, const bf16_t* __restrict__ Wm, const bf16_t* __restrict__ Wl,
    const void* __restrict__ b2, const void* __restrict__ ts, int t,
    const float* __restrict__ hprev_f32,
    float* __restrict__ houtf,
    bf16_t* __restrict__ houth, bf16_t* __restrict__ houtm, bf16_t* __restrict__ houtl,
    float* __restrict__ states, const int* __restrict__ flg)
{
  const int isf32 = *flg;
  f32x4 acc[2][2];
  gemm6<false>(th, tm, tl, 128, nullptr, 0, 0, Wh, Wm, Wl, 128, acc);
  float dt = loadf(ts, t + 1, isf32) - loadf(ts, t, isf32);
  float s = 0.5f * dt;
  EPI_COORDS
#pragma unroll
  for (int mi = 0; mi < 2; mi++)
#pragma unroll
    for (int ni = 0; ni < 2; ni++)
#pragma unroll
      for (int r = 0; r < 4; r++) {
        int m = row0 + mi * 16 + r;
        int n = col0 + ni * 16;
        int idx = m * 1024 + n;
        float hv = hprev_f32[idx] + s * (acc[mi][ni][r] + loadf(b2, n, isf32));
        hv = fminf(fmaxf(hv, -1e6f), 1e6f);   // insurance clamp
        houtf[idx] = hv;
        bf16_t h, mm_, l; split3(hv, h, mm_, l);
        houth[idx] = h; houtm[idx] = mm_; houtl[idx] = l;
        if (WRITE_STATES)
          states[((size_t)t * 512 + m) * 1024 + n] = hv;   // f32 output
      }
}

// ---------------- emit: logits = h@We + be
__global__ __launch_bounds__(256, 1) void k_emit(
    const bf16_t* __restrict__ hh, const bf16_t* __restrict__ hm, const bf16_t* __restrict__ hl,
    const bf16_t* __restrict__ Wh, const bf16_t* __restrict__ Wm, const bf16_t* __restrict__ Wl,
    const void* __restrict__ be, float* __restrict__ logits, const int* __restrict__ flg)
{
  const int isf32 = *flg;
  f32x4 acc[2][2];
  gemm6<false>(hh, hm, hl, 1024, nullptr, 0, 0, Wh, Wm, Wl, 1024, acc);
  EPI_COORDS
#pragma unroll
  for (int mi = 0; mi < 2; mi++)
#pragma unroll
    for (int ni = 0; ni < 2; ni++)
#pragma unroll
      for (int r = 0; r < 4; r++) {
        int m = row0 + mi * 16 + r;
        int n = col0 + ni * 16;
        logits[m * 256 + n] = acc[mi][ni][r] + loadf(be, n, isf32);
      }
}

// ---------------- row softmax over 256 (f32 output)
__global__ __launch_bounds__(256) void k_softmax(
    const float* __restrict__ logits, float* __restrict__ probs, int t)
{
  int m = blockIdx.x;
  int j = threadIdx.x;
  float v = logits[m * 256 + j];
  __shared__ float red[256];
  red[j] = v;
  __syncthreads();
  for (int s = 128; s > 0; s >>= 1) {
    if (j < s) red[j] = fmaxf(red[j], red[j + s]);
    __syncthreads();
  }
  float mx = red[0];
  __syncthreads();
  float e = expf(v - mx);
  red[j] = e;
  __syncthreads();
  for (int s = 128; s > 0; s >>= 1) {
    if (j < s) red[j] += red[j + s];
    __syncthreads();
  }
  probs[((size_t)t * 512 + m) * 256 + j] = e / red[0];
}

// ---------------- weight transpose+split into bf16x3 [Npad][Kpad], zero-padded
__global__ void k_transpose_split(const void* __restrict__ src,
                                  bf16_t* __restrict__ dh, bf16_t* __restrict__ dm,
                                  bf16_t* __restrict__ dl,
                                  int K, int N, int Kpad, const int* __restrict__ flg)
{
  const int isf32 = *flg;
  int k = blockIdx.x * 256 + threadIdx.x;
  if (k >= Kpad) return;
  int n = blockIdx.y;  // < Npad
  float v = 0.f;
  if (k < K && n < N) v = loadf(src, k * N + n, isf32);
  bf16_t h, m, l; split3(v, h, m, l);
  size_t idx = (size_t)n * Kpad + k;
  dh[idx] = h; dm[idx] = m; dl[idx] = l;
}

extern "C" void kernel_launch(void* const* d_in, const int* in_sizes, int n_in,
                              void* d_out, int out_size, void* d_ws, size_t ws_size,
                              hipStream_t stream) {
  const void* data = d_in[0];
  const void* ts   = d_in[1];
  const void* Wu   = d_in[2];
  const void* bu   = d_in[3];
  const void* Wr   = d_in[4];
  const void* br   = d_in[5];
  const void* Wn   = d_in[6];
  const void* bn   = d_in[7];
  const void* W1   = d_in[8];
  const void* b1   = d_in[9];
  const void* W2   = d_in[10];
  const void* b2   = d_in[11];
  const void* We   = d_in[12];
  const void* be   = d_in[13];

  float* out_probs  = (float*)d_out;
  float* out_states = (float*)d_out + (size_t)63 * 512 * 256;

  char* p = (char*)d_ws;
  auto carve = [&](size_t bytes) { char* r = p; p += (bytes + 255) & ~255ull; return (void*)r; };
  int*    flg   = (int*)carve(256);
  // weights: bf16x3, transposed [Npad][Kpad]
  bf16_t* WurTh = (bf16_t*)carve((size_t)2048 * 1536 * 2);
  bf16_t* WurTm = (bf16_t*)carve((size_t)2048 * 1536 * 2);
  bf16_t* WurTl = (bf16_t*)carve((size_t)2048 * 1536 * 2);
  bf16_t* WnTh  = (bf16_t*)carve((size_t)1024 * 1536 * 2);
  bf16_t* WnTm  = (bf16_t*)carve((size_t)1024 * 1536 * 2);
  bf16_t* WnTl  = (bf16_t*)carve((size_t)1024 * 1536 * 2);
  bf16_t* W1Th  = (bf16_t*)carve((size_t)128 * 1024 * 2);
  bf16_t* W1Tm  = (bf16_t*)carve((size_t)128 * 1024 * 2);
  bf16_t* W1Tl  = (bf16_t*)carve((size_t)128 * 1024 * 2);
  bf16_t* W2Th  = (bf16_t*)carve((size_t)1024 * 128 * 2);
  bf16_t* W2Tm  = (bf16_t*)carve((size_t)1024 * 128 * 2);
  bf16_t* W2Tl  = (bf16_t*)carve((size_t)1024 * 128 * 2);
  bf16_t* WeTh  = (bf16_t*)carve((size_t)256 * 1024 * 2);
  bf16_t* WeTm  = (bf16_t*)carve((size_t)256 * 1024 * 2);
  bf16_t* WeTl  = (bf16_t*)carve((size_t)256 * 1024 * 2);
  // states: f32 + bf16x3
  float*  P0f = (float*)carve((size_t)512 * 1024 * 4);
  float*  P1f = (float*)carve((size_t)512 * 1024 * 4);
  float*  P2f = (float*)carve((size_t)512 * 1024 * 4);
  bf16_t* P0h = (bf16_t*)carve((size_t)512 * 1024 * 2);
  bf16_t* P0m = (bf16_t*)carve((size_t)512 * 1024 * 2);
  bf16_t* P0l = (bf16_t*)carve((size_t)512 * 1024 * 2);
  bf16_t* P1h = (bf16_t*)carve((size_t)512 * 1024 * 2);
  bf16_t* P1m = (bf16_t*)carve((size_t)512 * 1024 * 2);
  bf16_t* P1l = (bf16_t*)carve((size_t)512 * 1024 * 2);
  bf16_t* P2h = (bf16_t*)carve((size_t)512 * 1024 * 2);
  bf16_t* P2m = (bf16_t*)carve((size_t)512 * 1024 * 2);
  bf16_t* P2l = (bf16_t*)carve((size_t)512 * 1024 * 2);
  bf16_t* HRh = (bf16_t*)carve((size_t)512 * 1024 * 2);
  bf16_t* HRm = (bf16_t*)carve((size_t)512 * 1024 * 2);
  bf16_t* HRl = (bf16_t*)carve((size_t)512 * 1024 * 2);
  float*  uf  = (float*)carve((size_t)512 * 1024 * 4);
  bf16_t* Th  = (bf16_t*)carve((size_t)512 * 128 * 2);
  bf16_t* Tm  = (bf16_t*)carve((size_t)512 * 128 * 2);
  bf16_t* Tl  = (bf16_t*)carve((size_t)512 * 128 * 2);
  float*  lg  = (float*)carve((size_t)512 * 256 * 4);

  // h0 = 0 (f32 and bf16x3 views)
  (void)hipMemsetAsync(P0f, 0, (size_t)512 * 1024 * 4, stream);
  (void)hipMemsetAsync(P0h, 0, (size_t)512 * 1024 * 2, stream);
  (void)hipMemsetAsync(P0m, 0, (size_t)512 * 1024 * 2, stream);
  (void)hipMemsetAsync(P0l, 0, (size_t)512 * 1024 * 2, stream);

  dim3 b256(256);
  k_probe<<<1, 1, 0, stream>>>((const unsigned int*)ts, flg);

  k_transpose_split<<<dim3(6, 1024), b256, 0, stream>>>(Wu, WurTh, WurTm, WurTl, 1536, 1024, 1536, flg);
  k_transpose_split<<<dim3(6, 1024), b256, 0, stream>>>(Wr, WurTh + (size_t)1024 * 1536,
                                                        WurTm + (size_t)1024 * 1536,
                                                        WurTl + (size_t)1024 * 1536, 1536, 1024, 1536, flg);
  k_transpose_split<<<dim3(6, 1024), b256, 0, stream>>>(Wn, WnTh, WnTm, WnTl, 1536, 1024, 1536, flg);
  k_transpose_split<<<dim3(4, 128),  b256, 0, stream>>>(W1, W1Th, W1Tm, W1Tl, 1024, 100, 1024, flg);
  k_transpose_split<<<dim3(1, 1024), b256, 0, stream>>>(W2, W2Th, W2Tm, W2Tl, 100, 1024, 128, flg);
  k_transpose_split<<<dim3(4, 256),  b256, 0, stream>>>(We, WeTh, WeTm, WeTl, 1024, 256, 1024, flg);

  for (int t = 0; t < 63; t++) {
    // chain: P0 (h) -> gates/cand -> P1 -> euler1 -> P2 -> euler2 -> P0 (next h)
    k_gates<<<dim3(32, 8), b256, 0, stream>>>(P0h, P0m, P0l, P0f, data, t,
                                              WurTh, WurTm, WurTl, bu, br,
                                              uf, HRh, HRm, HRl, flg);
    k_cand <<<dim3(16, 8), b256, 0, stream>>>(HRh, HRm, HRl, data, t,
                                              WnTh, WnTm, WnTl, bn, uf, P0f,
                                              P1f, P1h, P1m, P1l, flg);
    k_tanh <<<dim3(2, 8),  b256, 0, stream>>>(P1h, P1m, P1l, W1Th, W1Tm, W1Tl, b1,
                                              Th, Tm, Tl, flg);
    k_euler<false><<<dim3(16, 8), b256, 0, stream>>>(Th, Tm, Tl, W2Th, W2Tm, W2Tl, b2, ts, t,
                                                     P1f, P2f, P2h, P2m, P2l, nullptr, flg);
    k_tanh <<<dim3(2, 8),  b256, 0, stream>>>(P2h, P2m, P2l, W1Th, W1Tm, W1Tl, b1,
                                              Th, Tm, Tl, flg);
    k_euler<true> <<<dim3(16, 8), b256, 0, stream>>>(Th, Tm, Tl, W2Th, W2Tm, W2Tl, b2, ts, t,
                                                     P2f, P0f, P0h, P0m, P0l, out_states, flg);
    k_emit <<<dim3(4, 8),  b256, 0, stream>>>(P0h, P0m, P0l, WeTh, WeTm, WeTl, be, lg, flg);
    k_softmax<<<512, b256, 0, stream>>>(lg, out_probs, t);
  }
}